// Round 1
// baseline (411.747 us; speedup 1.0000x reference)
//
#include <hip/hip_runtime.h>
#include <hip/hip_bf16.h>

// ---------- types ----------
typedef short short8 __attribute__((ext_vector_type(8)));
typedef float f32x4 __attribute__((ext_vector_type(4)));

#define N_TOKENS 2048
#define D_MODEL 1024
#define D_FF 4096
#define N_EXPERTS 8
#define TOTAL_SLOTS (N_TOKENS * 2)

static __device__ __forceinline__ unsigned int f2u(float f) {
    union { float f; unsigned int u; } v; v.f = f; return v.u;
}

// fp32 -> bf16 bits, round-to-nearest-even
static __device__ __forceinline__ unsigned short f2bf(float f) {
    unsigned int u = f2u(f);
    unsigned int r = (u + 0x7fffu + ((u >> 16) & 1u)) >> 16;
    return (unsigned short)r;
}

// ---------- kernel 1: x fp32 -> bf16 ----------
__global__ __launch_bounds__(256) void cvt_x_kernel(const float* __restrict__ x,
                                                    unsigned short* __restrict__ xb) {
    int i = (blockIdx.x * 256 + threadIdx.x) * 4;
    if (i >= N_TOKENS * D_MODEL) return;
    float4 f = *(const float4*)(x + i);
    uint2 o;
    o.x = (unsigned int)f2bf(f.x) | ((unsigned int)f2bf(f.y) << 16);
    o.y = (unsigned int)f2bf(f.z) | ((unsigned int)f2bf(f.w) << 16);
    *(uint2*)(xb + i) = o;
}

// ---------- kernel 2: gating (exact fp32) ----------
__global__ __launch_bounds__(64) void gate_kernel(const float* __restrict__ x,
                                                  const float* __restrict__ gw,
                                                  int* __restrict__ counts,
                                                  int* __restrict__ tok_e,
                                                  float* __restrict__ tok_w) {
    const int n = blockIdx.x;
    const int lane = threadIdx.x;
    float p[N_EXPERTS];
#pragma unroll
    for (int e = 0; e < N_EXPERTS; ++e) p[e] = 0.f;
    const float* xr = x + n * D_MODEL;
    for (int d = lane; d < D_MODEL; d += 64) {
        float xv = xr[d];
#pragma unroll
        for (int e = 0; e < N_EXPERTS; ++e) p[e] += xv * gw[e * D_MODEL + d];
    }
#pragma unroll
    for (int e = 0; e < N_EXPERTS; ++e) {
        float v = p[e];
        for (int o = 32; o > 0; o >>= 1) v += __shfl_down(v, o);
        p[e] = v;
    }
    if (lane == 0) {
        int b1 = 0; float v1 = p[0];
        for (int e = 1; e < N_EXPERTS; ++e) if (p[e] > v1) { v1 = p[e]; b1 = e; }
        int b2 = -1; float v2 = -1e30f;
        for (int e = 0; e < N_EXPERTS; ++e) if (e != b1 && p[e] > v2) { v2 = p[e]; b2 = e; }
        // softmax over the two selected logits (v1 >= v2)
        float e1 = __expf(0.f);                 // = 1
        float e2 = __expf(v2 - v1);
        float s = e1 + e2;
        tok_e[n * 2 + 0] = b1; tok_w[n * 2 + 0] = e1 / s;
        tok_e[n * 2 + 1] = b2; tok_w[n * 2 + 1] = e2 / s;
        atomicAdd(&counts[b1], 1);
        atomicAdd(&counts[b2], 1);
    }
}

// ---------- kernel 3: exclusive scan of 8 counts ----------
__global__ void scan_kernel(const int* __restrict__ counts,
                            int* __restrict__ offsets, int* __restrict__ fill) {
    if (threadIdx.x == 0 && blockIdx.x == 0) {
        int s = 0;
        for (int e = 0; e < N_EXPERTS; ++e) { offsets[e] = s; fill[e] = s; s += counts[e]; }
    }
}

// ---------- kernel 4: route tokens into contiguous per-expert slots ----------
__global__ __launch_bounds__(256) void route_kernel(const int* __restrict__ tok_e,
                                                    const float* __restrict__ tok_w,
                                                    int* __restrict__ fill,
                                                    int* __restrict__ rows_tok,
                                                    float* __restrict__ rows_w) {
    int i = blockIdx.x * 256 + threadIdx.x;
    if (i >= TOTAL_SLOTS) return;
    int e = tok_e[i];
    float w = tok_w[i];
    int pos = atomicAdd(&fill[e], 1);
    rows_tok[pos] = i >> 1;
    rows_w[pos] = w;
}

// ---------- kernel 5: GEMM1  h = gelu(x_gathered @ w1[e]^T), bf16 out ----------
// grid: (D_FF/128, 16, 8), block 256
__global__ __launch_bounds__(256) void gemm1_kernel(const unsigned short* __restrict__ xb,
                                                    const float* __restrict__ w1,
                                                    const int* __restrict__ counts,
                                                    const int* __restrict__ offsets,
                                                    const int* __restrict__ rows_tok,
                                                    unsigned short* __restrict__ h) {
    const int e = blockIdx.z;
    const int cnt = counts[e];
    const int mt = blockIdx.y;
    if (mt * 128 >= cnt) return;
    const int off = offsets[e];
    const int nt = blockIdx.x;

    __shared__ unsigned short As[128 * 32];
    __shared__ unsigned short Bs[128 * 32];

    const int tid = threadIdx.x;
    const int lane = tid & 63;
    const int wave = tid >> 6;
    const int wm = wave >> 1, wn = wave & 1;

    // A staging: rows r0 (=tid/4) and r0+64; 8 bf16 (16B) per row-chunk, c8 = tid&3
    const int r0 = tid >> 2, c8 = tid & 3;
    int g0 = off + mt * 128 + r0;          if (g0 > TOTAL_SLOTS - 1) g0 = TOTAL_SLOTS - 1;
    int g1 = off + mt * 128 + r0 + 64;     if (g1 > TOTAL_SLOTS - 1) g1 = TOTAL_SLOTS - 1;
    const int tok0 = rows_tok[g0];
    const int tok1 = rows_tok[g1];
    const unsigned short* a0 = xb + (size_t)tok0 * D_MODEL + c8 * 8;
    const unsigned short* a1 = xb + (size_t)tok1 * D_MODEL + c8 * 8;

    // B staging: row rb = tid/2 (0..127), 16 consecutive floats at col (tid&1)*16
    const int rb = tid >> 1, cb = (tid & 1) * 16;
    const float* bp = w1 + (size_t)e * (D_FF * D_MODEL) + (size_t)(nt * 128 + rb) * D_MODEL + cb;

    f32x4 acc[4][4];
#pragma unroll
    for (int i = 0; i < 4; ++i)
#pragma unroll
        for (int j = 0; j < 4; ++j) acc[i][j] = (f32x4){0.f, 0.f, 0.f, 0.f};

    for (int k0 = 0; k0 < D_MODEL; k0 += 32) {
        *(uint4*)&As[r0 * 32 + c8 * 8]        = *(const uint4*)(a0 + k0);
        *(uint4*)&As[(r0 + 64) * 32 + c8 * 8] = *(const uint4*)(a1 + k0);
        unsigned int bpack[8];
#pragma unroll
        for (int i = 0; i < 4; ++i) {
            float4 f = *(const float4*)(bp + k0 + i * 4);
            bpack[i * 2 + 0] = (unsigned int)f2bf(f.x) | ((unsigned int)f2bf(f.y) << 16);
            bpack[i * 2 + 1] = (unsigned int)f2bf(f.z) | ((unsigned int)f2bf(f.w) << 16);
        }
        *(uint4*)&Bs[rb * 32 + cb]     = *(uint4*)&bpack[0];
        *(uint4*)&Bs[rb * 32 + cb + 8] = *(uint4*)&bpack[4];
        __syncthreads();

        short8 af[4], bfr[4];
#pragma unroll
        for (int mi = 0; mi < 4; ++mi)
            af[mi] = *(const short8*)&As[(wm * 64 + mi * 16 + (lane & 15)) * 32 + (lane >> 4) * 8];
#pragma unroll
        for (int nj = 0; nj < 4; ++nj)
            bfr[nj] = *(const short8*)&Bs[(wn * 64 + nj * 16 + (lane & 15)) * 32 + (lane >> 4) * 8];
#pragma unroll
        for (int mi = 0; mi < 4; ++mi)
#pragma unroll
            for (int nj = 0; nj < 4; ++nj)
                acc[mi][nj] = __builtin_amdgcn_mfma_f32_16x16x32_bf16(af[mi], bfr[nj], acc[mi][nj], 0, 0, 0);
        __syncthreads();
    }

    // epilogue: exact-erf GELU, store bf16
    const int lr = (lane >> 4) * 4, lc = lane & 15;
#pragma unroll
    for (int mi = 0; mi < 4; ++mi) {
        const int mbase = mt * 128 + wm * 64 + mi * 16 + lr;
#pragma unroll
        for (int j = 0; j < 4; ++j) {
            const int m = mbase + j;
            if (m < cnt) {
#pragma unroll
                for (int nj = 0; nj < 4; ++nj) {
                    const int n = nt * 128 + wn * 64 + nj * 16 + lc;
                    float v = acc[mi][nj][j];
                    v = 0.5f * v * (1.0f + erff(v * 0.70710678118654752f));
                    h[(size_t)(off + m) * D_FF + n] = f2bf(v);
                }
            }
        }
    }
}

// ---------- kernel 6: GEMM2  out[tok] += w_slot * (h @ w2[e]^T) ----------
// grid: (D_MODEL/128, 16, 8), block 256
__global__ __launch_bounds__(256) void gemm2_kernel(const unsigned short* __restrict__ h,
                                                    const float* __restrict__ w2,
                                                    const int* __restrict__ counts,
                                                    const int* __restrict__ offsets,
                                                    const int* __restrict__ rows_tok,
                                                    const float* __restrict__ rows_w,
                                                    float* __restrict__ out) {
    const int e = blockIdx.z;
    const int cnt = counts[e];
    const int mt = blockIdx.y;
    if (mt * 128 >= cnt) return;
    const int off = offsets[e];
    const int nt = blockIdx.x;

    __shared__ unsigned short As[128 * 32];
    __shared__ unsigned short Bs[128 * 32];

    const int tid = threadIdx.x;
    const int lane = tid & 63;
    const int wave = tid >> 6;
    const int wm = wave >> 1, wn = wave & 1;

    const int r0 = tid >> 2, c8 = tid & 3;
    int g0 = off + mt * 128 + r0;          if (g0 > TOTAL_SLOTS - 1) g0 = TOTAL_SLOTS - 1;
    int g1 = off + mt * 128 + r0 + 64;     if (g1 > TOTAL_SLOTS - 1) g1 = TOTAL_SLOTS - 1;
    const unsigned short* a0 = h + (size_t)g0 * D_FF + c8 * 8;
    const unsigned short* a1 = h + (size_t)g1 * D_FF + c8 * 8;

    const int rb = tid >> 1, cb = (tid & 1) * 16;
    const float* bp = w2 + (size_t)e * (D_MODEL * D_FF) + (size_t)(nt * 128 + rb) * D_FF + cb;

    f32x4 acc[4][4];
#pragma unroll
    for (int i = 0; i < 4; ++i)
#pragma unroll
        for (int j = 0; j < 4; ++j) acc[i][j] = (f32x4){0.f, 0.f, 0.f, 0.f};

    for (int k0 = 0; k0 < D_FF; k0 += 32) {
        *(uint4*)&As[r0 * 32 + c8 * 8]        = *(const uint4*)(a0 + k0);
        *(uint4*)&As[(r0 + 64) * 32 + c8 * 8] = *(const uint4*)(a1 + k0);
        unsigned int bpack[8];
#pragma unroll
        for (int i = 0; i < 4; ++i) {
            float4 f = *(const float4*)(bp + k0 + i * 4);
            bpack[i * 2 + 0] = (unsigned int)f2bf(f.x) | ((unsigned int)f2bf(f.y) << 16);
            bpack[i * 2 + 1] = (unsigned int)f2bf(f.z) | ((unsigned int)f2bf(f.w) << 16);
        }
        *(uint4*)&Bs[rb * 32 + cb]     = *(uint4*)&bpack[0];
        *(uint4*)&Bs[rb * 32 + cb + 8] = *(uint4*)&bpack[4];
        __syncthreads();

        short8 af[4], bfr[4];
#pragma unroll
        for (int mi = 0; mi < 4; ++mi)
            af[mi] = *(const short8*)&As[(wm * 64 + mi * 16 + (lane & 15)) * 32 + (lane >> 4) * 8];
#pragma unroll
        for (int nj = 0; nj < 4; ++nj)
            bfr[nj] = *(const short8*)&Bs[(wn * 64 + nj * 16 + (lane & 15)) * 32 + (lane >> 4) * 8];
#pragma unroll
        for (int mi = 0; mi < 4; ++mi)
#pragma unroll
            for (int nj = 0; nj < 4; ++nj)
                acc[mi][nj] = __builtin_amdgcn_mfma_f32_16x16x32_bf16(af[mi], bfr[nj], acc[mi][nj], 0, 0, 0);
        __syncthreads();
    }

    const int lr = (lane >> 4) * 4, lc = lane & 15;
#pragma unroll
    for (int mi = 0; mi < 4; ++mi) {
        const int mbase = mt * 128 + wm * 64 + mi * 16 + lr;
#pragma unroll
        for (int j = 0; j < 4; ++j) {
            const int m = mbase + j;
            if (m < cnt) {
                const int tok = rows_tok[off + m];
                const float w = rows_w[off + m];
#pragma unroll
                for (int nj = 0; nj < 4; ++nj) {
                    const int n = nt * 128 + wn * 64 + nj * 16 + lc;
                    atomicAdd(&out[(size_t)tok * D_MODEL + n], w * acc[mi][nj][j]);
                }
            }
        }
    }
}

// ---------- workspace layout ----------
//   0      counts[8]
//   256    fill[8]
//   512    offsets[8]
//   768    tok_e   [4096] int      (16384 B)
//   17152  tok_w   [4096] float    (16384 B)
//   33536  rows_tok[4096] int      (16384 B)
//   49920  rows_w  [4096] float    (16384 B)
//   66560  xb  bf16 [2048][1024]   (4 MB)
//   4261120  h  bf16 [4096][4096]  (32 MB)
// total ~36.2 MB

extern "C" void kernel_launch(void* const* d_in, const int* in_sizes, int n_in,
                              void* d_out, int out_size, void* d_ws, size_t ws_size,
                              hipStream_t stream) {
    const float* x  = (const float*)d_in[0];
    const float* gw = (const float*)d_in[1];
    const float* w1 = (const float*)d_in[2];
    const float* w2 = (const float*)d_in[3];
    float* out = (float*)d_out;

    char* ws = (char*)d_ws;
    int*   counts   = (int*)(ws + 0);
    int*   fill     = (int*)(ws + 256);
    int*   offsets  = (int*)(ws + 512);
    int*   tok_e    = (int*)(ws + 768);
    float* tok_w    = (float*)(ws + 17152);
    int*   rows_tok = (int*)(ws + 33536);
    float* rows_w   = (float*)(ws + 49920);
    unsigned short* xb = (unsigned short*)(ws + 66560);
    unsigned short* h  = (unsigned short*)(ws + 66560 + (size_t)N_TOKENS * D_MODEL * 2);

    hipMemsetAsync(counts, 0, 32, stream);
    hipMemsetAsync(d_out, 0, (size_t)out_size * sizeof(float), stream);

    cvt_x_kernel<<<dim3((N_TOKENS * D_MODEL / 4 + 255) / 256), dim3(256), 0, stream>>>(x, xb);
    gate_kernel<<<dim3(N_TOKENS), dim3(64), 0, stream>>>(x, gw, counts, tok_e, tok_w);
    scan_kernel<<<dim3(1), dim3(64), 0, stream>>>(counts, offsets, fill);
    route_kernel<<<dim3((TOTAL_SLOTS + 255) / 256), dim3(256), 0, stream>>>(tok_e, tok_w, fill, rows_tok, rows_w);
    gemm1_kernel<<<dim3(D_FF / 128, 16, N_EXPERTS), dim3(256), 0, stream>>>(xb, w1, counts, offsets, rows_tok, h);
    gemm2_kernel<<<dim3(D_MODEL / 128, 16, N_EXPERTS), dim3(256), 0, stream>>>(h, w2, counts, offsets, rows_tok, rows_w, out);
}

// Round 2
// 334.829 us; speedup vs baseline: 1.2297x; 1.2297x over previous
//
#include <hip/hip_runtime.h>
#include <hip/hip_bf16.h>

// ---------- types ----------
typedef short short8 __attribute__((ext_vector_type(8)));
typedef float f32x4 __attribute__((ext_vector_type(4)));

#define N_TOKENS 2048
#define D_MODEL 1024
#define D_FF 4096
#define N_EXPERTS 8
#define TOTAL_SLOTS (N_TOKENS * 2)
#define BK 32
#define SPLITK2 4
#define KC2 (D_FF / SPLITK2)   // 1024 K per gemm2 block

static __device__ __forceinline__ unsigned int f2u(float f) {
    union { float f; unsigned int u; } v; v.f = f; return v.u;
}

// fp32 -> bf16 bits, round-to-nearest-even (scalar path)
static __device__ __forceinline__ unsigned short f2bf(float f) {
    unsigned int u = f2u(f);
    unsigned int r = (u + 0x7fffu + ((u >> 16) & 1u)) >> 16;
    return (unsigned short)r;
}

// two fp32 -> packed bf16x2 (compiler emits v_cvt_pk_bf16_f32)
static __device__ __forceinline__ unsigned int pk2bf(float a, float b) {
    __hip_bfloat162 t = __float22bfloat162_rn(float2{a, b});
    unsigned int u;
    __builtin_memcpy(&u, &t, 4);
    return u;
}

// async global->LDS, 16B per lane. LDS dest must be wave-uniform base;
// lane l lands at base + l*16 (guide §5: wave-uniform base + lane*size).
typedef __attribute__((address_space(1))) const unsigned int GU;
typedef __attribute__((address_space(3))) unsigned int LU;
static __device__ __forceinline__ void gload_lds16(const void* g, void* l) {
    __builtin_amdgcn_global_load_lds((GU*)g, (LU*)l, 16, 0, 0);
}

// ---------- kernel 1: x fp32 -> bf16 ----------
__global__ __launch_bounds__(256) void cvt_x_kernel(const float* __restrict__ x,
                                                    unsigned short* __restrict__ xb) {
    int i = (blockIdx.x * 256 + threadIdx.x) * 4;
    if (i >= N_TOKENS * D_MODEL) return;
    float4 f = *(const float4*)(x + i);
    uint2 o;
    o.x = pk2bf(f.x, f.y);
    o.y = pk2bf(f.z, f.w);
    *(uint2*)(xb + i) = o;
}

// ---------- kernel 2: gating (exact fp32) ----------
__global__ __launch_bounds__(64) void gate_kernel(const float* __restrict__ x,
                                                  const float* __restrict__ gw,
                                                  int* __restrict__ counts,
                                                  int* __restrict__ tok_e,
                                                  float* __restrict__ tok_w) {
    const int n = blockIdx.x;
    const int lane = threadIdx.x;
    float p[N_EXPERTS];
#pragma unroll
    for (int e = 0; e < N_EXPERTS; ++e) p[e] = 0.f;
    const float* xr = x + n * D_MODEL;
    for (int d = lane; d < D_MODEL; d += 64) {
        float xv = xr[d];
#pragma unroll
        for (int e = 0; e < N_EXPERTS; ++e) p[e] += xv * gw[e * D_MODEL + d];
    }
#pragma unroll
    for (int e = 0; e < N_EXPERTS; ++e) {
        float v = p[e];
        for (int o = 32; o > 0; o >>= 1) v += __shfl_down(v, o);
        p[e] = v;
    }
    if (lane == 0) {
        int b1 = 0; float v1 = p[0];
        for (int e = 1; e < N_EXPERTS; ++e) if (p[e] > v1) { v1 = p[e]; b1 = e; }
        int b2 = -1; float v2 = -1e30f;
        for (int e = 0; e < N_EXPERTS; ++e) if (e != b1 && p[e] > v2) { v2 = p[e]; b2 = e; }
        float e2 = __expf(v2 - v1);
        float s = 1.f + e2;
        tok_e[n * 2 + 0] = b1; tok_w[n * 2 + 0] = 1.f / s;
        tok_e[n * 2 + 1] = b2; tok_w[n * 2 + 1] = e2 / s;
        atomicAdd(&counts[b1], 1);
        atomicAdd(&counts[b2], 1);
    }
}

// ---------- kernel 3: exclusive scan of 8 counts ----------
__global__ void scan_kernel(const int* __restrict__ counts,
                            int* __restrict__ offsets, int* __restrict__ fill) {
    if (threadIdx.x == 0 && blockIdx.x == 0) {
        int s = 0;
        for (int e = 0; e < N_EXPERTS; ++e) { offsets[e] = s; fill[e] = s; s += counts[e]; }
    }
}

// ---------- kernel 4: route tokens into contiguous per-expert slots ----------
__global__ __launch_bounds__(256) void route_kernel(const int* __restrict__ tok_e,
                                                    const float* __restrict__ tok_w,
                                                    int* __restrict__ fill,
                                                    int* __restrict__ rows_tok,
                                                    float* __restrict__ rows_w) {
    int i = blockIdx.x * 256 + threadIdx.x;
    if (i >= TOTAL_SLOTS) return;
    int e = tok_e[i];
    float w = tok_w[i];
    int pos = atomicAdd(&fill[e], 1);
    rows_tok[pos] = i >> 1;
    rows_w[pos] = w;
}

// ---------- kernel 5: GEMM1  h = gelu(x_gathered @ w1[e]^T), bf16 out ----------
// 128x128 tile, BK=32, double-buffered LDS, 2-phase prefetch.
// grid: (D_FF/128, 16, 8), block 256
__global__ __launch_bounds__(256, 3) void gemm1_kernel(const unsigned short* __restrict__ xb,
                                                       const float* __restrict__ w1,
                                                       const int* __restrict__ counts,
                                                       const int* __restrict__ offsets,
                                                       const int* __restrict__ rows_tok,
                                                       unsigned short* __restrict__ h) {
    const int e = blockIdx.z;
    const int cnt = counts[e];
    const int mt = blockIdx.y;
    if (mt * 128 >= cnt) return;
    const int off = offsets[e];
    const int nt = blockIdx.x;

    __shared__ unsigned short As[2][128 * 32];
    __shared__ unsigned short Bs[2][128 * 32];

    const int tid = threadIdx.x;
    const int lane = tid & 63;
    const int wave = tid >> 6;
    const int wm = wave >> 1, wn = wave & 1;

    // A staging via global_load_lds: wave stages rows [wave*32, wave*32+32)
    // in 2 instructions of 16 rows; lane l -> row (l>>2), 16B chunk (l&3).
    const int arow = wave * 32 + (lane >> 2);
    const int ac8 = lane & 3;
    int r0 = off + mt * 128 + arow;
    int r1 = r0 + 16;
    r0 = min(r0, TOTAL_SLOTS - 1);
    r1 = min(r1, TOTAL_SLOTS - 1);
    const unsigned short* ag0 = xb + (size_t)rows_tok[r0] * D_MODEL + ac8 * 8;
    const unsigned short* ag1 = xb + (size_t)rows_tok[r1] * D_MODEL + ac8 * 8;
    unsigned short* al0_0 = &As[0][(wave * 32) * 32];
    unsigned short* al1_0 = &As[0][(wave * 32 + 16) * 32];
    unsigned short* al0_1 = &As[1][(wave * 32) * 32];
    unsigned short* al1_1 = &As[1][(wave * 32 + 16) * 32];

    // B staging (reg): row tid>>1, 16 fp32 at col (tid&1)*16
    const int brow = tid >> 1, bcol = (tid & 1) * 16;
    const float* bg = w1 + (size_t)e * (D_FF * D_MODEL) + (size_t)(nt * 128 + brow) * D_MODEL + bcol;

    f32x4 acc[4][4];
#pragma unroll
    for (int i = 0; i < 4; ++i)
#pragma unroll
        for (int j = 0; j < 4; ++j) acc[i][j] = (f32x4){0.f, 0.f, 0.f, 0.f};

    // ---- prologue: stage tile 0 into buffer 0
    {
        gload_lds16(ag0, al0_0);
        gload_lds16(ag1, al1_0);
        float4 fb0 = *(const float4*)(bg + 0);
        float4 fb1 = *(const float4*)(bg + 4);
        float4 fb2 = *(const float4*)(bg + 8);
        float4 fb3 = *(const float4*)(bg + 12);
        unsigned int bp[8];
        bp[0] = pk2bf(fb0.x, fb0.y); bp[1] = pk2bf(fb0.z, fb0.w);
        bp[2] = pk2bf(fb1.x, fb1.y); bp[3] = pk2bf(fb1.z, fb1.w);
        bp[4] = pk2bf(fb2.x, fb2.y); bp[5] = pk2bf(fb2.z, fb2.w);
        bp[6] = pk2bf(fb3.x, fb3.y); bp[7] = pk2bf(fb3.z, fb3.w);
        *(uint4*)&Bs[0][brow * 32 + bcol]     = *(uint4*)&bp[0];
        *(uint4*)&Bs[0][brow * 32 + bcol + 8] = *(uint4*)&bp[4];
    }
    __syncthreads();

    const int KSTEPS = D_MODEL / BK;  // 32
#pragma unroll 2
    for (int t = 0; t < KSTEPS; ++t) {
        const int cur = t & 1;
        const bool more = (t + 1 < KSTEPS);
        float4 fb0, fb1, fb2, fb3;
        if (more) {
            const int k1 = (t + 1) * BK;
            fb0 = *(const float4*)(bg + k1 + 0);
            fb1 = *(const float4*)(bg + k1 + 4);
            fb2 = *(const float4*)(bg + k1 + 8);
            fb3 = *(const float4*)(bg + k1 + 12);
            gload_lds16(ag0 + k1, cur ? al0_0 : al0_1);
            gload_lds16(ag1 + k1, cur ? al1_0 : al1_1);
        }
        short8 af[4], bfr[4];
#pragma unroll
        for (int mi = 0; mi < 4; ++mi)
            af[mi] = *(const short8*)&As[cur][(wm * 64 + mi * 16 + (lane & 15)) * 32 + (lane >> 4) * 8];
#pragma unroll
        for (int nj = 0; nj < 4; ++nj)
            bfr[nj] = *(const short8*)&Bs[cur][(wn * 64 + nj * 16 + (lane & 15)) * 32 + (lane >> 4) * 8];
#pragma unroll
        for (int mi = 0; mi < 4; ++mi)
#pragma unroll
            for (int nj = 0; nj < 4; ++nj)
                acc[mi][nj] = __builtin_amdgcn_mfma_f32_16x16x32_bf16(af[mi], bfr[nj], acc[mi][nj], 0, 0, 0);
        if (more) {
            unsigned int bp[8];
            bp[0] = pk2bf(fb0.x, fb0.y); bp[1] = pk2bf(fb0.z, fb0.w);
            bp[2] = pk2bf(fb1.x, fb1.y); bp[3] = pk2bf(fb1.z, fb1.w);
            bp[4] = pk2bf(fb2.x, fb2.y); bp[5] = pk2bf(fb2.z, fb2.w);
            bp[6] = pk2bf(fb3.x, fb3.y); bp[7] = pk2bf(fb3.z, fb3.w);
            const int nb = cur ^ 1;
            *(uint4*)&Bs[nb][brow * 32 + bcol]     = *(uint4*)&bp[0];
            *(uint4*)&Bs[nb][brow * 32 + bcol + 8] = *(uint4*)&bp[4];
        }
        __syncthreads();
    }

    // epilogue: exact-erf GELU, store bf16
    const int lr = (lane >> 4) * 4, lc = lane & 15;
#pragma unroll
    for (int mi = 0; mi < 4; ++mi) {
        const int mbase = mt * 128 + wm * 64 + mi * 16 + lr;
#pragma unroll
        for (int j = 0; j < 4; ++j) {
            const int m = mbase + j;
            if (m < cnt) {
#pragma unroll
                for (int nj = 0; nj < 4; ++nj) {
                    const int n = nt * 128 + wn * 64 + nj * 16 + lc;
                    float v = acc[mi][nj][j];
                    v = 0.5f * v * (1.0f + erff(v * 0.70710678118654752f));
                    h[(size_t)(off + m) * D_FF + n] = f2bf(v);
                }
            }
        }
    }
}

// ---------- kernel 6: GEMM2  out[tok] += w_slot * (h @ w2[e]^T), split-K x4 ----------
// grid: (D_MODEL/128, 16, 8*SPLITK2), block 256
__global__ __launch_bounds__(256, 3) void gemm2_kernel(const unsigned short* __restrict__ h,
                                                       const float* __restrict__ w2,
                                                       const int* __restrict__ counts,
                                                       const int* __restrict__ offsets,
                                                       const int* __restrict__ rows_tok,
                                                       const float* __restrict__ rows_w,
                                                       float* __restrict__ out) {
    const int e = blockIdx.z >> 2;
    const int kc = blockIdx.z & 3;
    const int cnt = counts[e];
    const int mt = blockIdx.y;
    if (mt * 128 >= cnt) return;
    const int off = offsets[e];
    const int nt = blockIdx.x;

    __shared__ unsigned short As[2][128 * 32];
    __shared__ unsigned short Bs[2][128 * 32];

    const int tid = threadIdx.x;
    const int lane = tid & 63;
    const int wave = tid >> 6;
    const int wm = wave >> 1, wn = wave & 1;

    const int arow = wave * 32 + (lane >> 2);
    const int ac8 = lane & 3;
    int r0 = off + mt * 128 + arow;
    int r1 = r0 + 16;
    r0 = min(r0, TOTAL_SLOTS - 1);
    r1 = min(r1, TOTAL_SLOTS - 1);
    const unsigned short* ag0 = h + (size_t)r0 * D_FF + kc * KC2 + ac8 * 8;
    const unsigned short* ag1 = h + (size_t)r1 * D_FF + kc * KC2 + ac8 * 8;
    unsigned short* al0_0 = &As[0][(wave * 32) * 32];
    unsigned short* al1_0 = &As[0][(wave * 32 + 16) * 32];
    unsigned short* al0_1 = &As[1][(wave * 32) * 32];
    unsigned short* al1_1 = &As[1][(wave * 32 + 16) * 32];

    const int brow = tid >> 1, bcol = (tid & 1) * 16;
    const float* bg = w2 + (size_t)e * (D_MODEL * D_FF) + (size_t)(nt * 128 + brow) * D_FF
                      + kc * KC2 + bcol;

    f32x4 acc[4][4];
#pragma unroll
    for (int i = 0; i < 4; ++i)
#pragma unroll
        for (int j = 0; j < 4; ++j) acc[i][j] = (f32x4){0.f, 0.f, 0.f, 0.f};

    {
        gload_lds16(ag0, al0_0);
        gload_lds16(ag1, al1_0);
        float4 fb0 = *(const float4*)(bg + 0);
        float4 fb1 = *(const float4*)(bg + 4);
        float4 fb2 = *(const float4*)(bg + 8);
        float4 fb3 = *(const float4*)(bg + 12);
        unsigned int bp[8];
        bp[0] = pk2bf(fb0.x, fb0.y); bp[1] = pk2bf(fb0.z, fb0.w);
        bp[2] = pk2bf(fb1.x, fb1.y); bp[3] = pk2bf(fb1.z, fb1.w);
        bp[4] = pk2bf(fb2.x, fb2.y); bp[5] = pk2bf(fb2.z, fb2.w);
        bp[6] = pk2bf(fb3.x, fb3.y); bp[7] = pk2bf(fb3.z, fb3.w);
        *(uint4*)&Bs[0][brow * 32 + bcol]     = *(uint4*)&bp[0];
        *(uint4*)&Bs[0][brow * 32 + bcol + 8] = *(uint4*)&bp[4];
    }
    __syncthreads();

    const int KSTEPS = KC2 / BK;  // 32
#pragma unroll 2
    for (int t = 0; t < KSTEPS; ++t) {
        const int cur = t & 1;
        const bool more = (t + 1 < KSTEPS);
        float4 fb0, fb1, fb2, fb3;
        if (more) {
            const int k1 = (t + 1) * BK;
            fb0 = *(const float4*)(bg + k1 + 0);
            fb1 = *(const float4*)(bg + k1 + 4);
            fb2 = *(const float4*)(bg + k1 + 8);
            fb3 = *(const float4*)(bg + k1 + 12);
            gload_lds16(ag0 + k1, cur ? al0_0 : al0_1);
            gload_lds16(ag1 + k1, cur ? al1_0 : al1_1);
        }
        short8 af[4], bfr[4];
#pragma unroll
        for (int mi = 0; mi < 4; ++mi)
            af[mi] = *(const short8*)&As[cur][(wm * 64 + mi * 16 + (lane & 15)) * 32 + (lane >> 4) * 8];
#pragma unroll
        for (int nj = 0; nj < 4; ++nj)
            bfr[nj] = *(const short8*)&Bs[cur][(wn * 64 + nj * 16 + (lane & 15)) * 32 + (lane >> 4) * 8];
#pragma unroll
        for (int mi = 0; mi < 4; ++mi)
#pragma unroll
            for (int nj = 0; nj < 4; ++nj)
                acc[mi][nj] = __builtin_amdgcn_mfma_f32_16x16x32_bf16(af[mi], bfr[nj], acc[mi][nj], 0, 0, 0);
        if (more) {
            unsigned int bp[8];
            bp[0] = pk2bf(fb0.x, fb0.y); bp[1] = pk2bf(fb0.z, fb0.w);
            bp[2] = pk2bf(fb1.x, fb1.y); bp[3] = pk2bf(fb1.z, fb1.w);
            bp[4] = pk2bf(fb2.x, fb2.y); bp[5] = pk2bf(fb2.z, fb2.w);
            bp[6] = pk2bf(fb3.x, fb3.y); bp[7] = pk2bf(fb3.z, fb3.w);
            const int nb = cur ^ 1;
            *(uint4*)&Bs[nb][brow * 32 + bcol]     = *(uint4*)&bp[0];
            *(uint4*)&Bs[nb][brow * 32 + bcol + 8] = *(uint4*)&bp[4];
        }
        __syncthreads();
    }

    const int lr = (lane >> 4) * 4, lc = lane & 15;
#pragma unroll
    for (int mi = 0; mi < 4; ++mi) {
        const int mbase = mt * 128 + wm * 64 + mi * 16 + lr;
#pragma unroll
        for (int j = 0; j < 4; ++j) {
            const int m = mbase + j;
            if (m < cnt) {
                const int tok = rows_tok[off + m];
                const float w = rows_w[off + m];
#pragma unroll
                for (int nj = 0; nj < 4; ++nj) {
                    const int n = nt * 128 + wn * 64 + nj * 16 + lc;
                    atomicAdd(&out[(size_t)tok * D_MODEL + n], w * acc[mi][nj][j]);
                }
            }
        }
    }
}

// ---------- workspace layout ----------
//   0        counts[8]
//   256      fill[8]
//   512      offsets[8]
//   768      tok_e   [4096] int
//   17152    tok_w   [4096] float
//   33536    rows_tok[4096] int
//   49920    rows_w  [4096] float
//   66560    xb  bf16 [2048][1024]   (4 MB)
//   +4MB     h   bf16 [4096][4096]   (32 MB)

extern "C" void kernel_launch(void* const* d_in, const int* in_sizes, int n_in,
                              void* d_out, int out_size, void* d_ws, size_t ws_size,
                              hipStream_t stream) {
    const float* x  = (const float*)d_in[0];
    const float* gw = (const float*)d_in[1];
    const float* w1 = (const float*)d_in[2];
    const float* w2 = (const float*)d_in[3];
    float* out = (float*)d_out;

    char* ws = (char*)d_ws;
    int*   counts   = (int*)(ws + 0);
    int*   fill     = (int*)(ws + 256);
    int*   offsets  = (int*)(ws + 512);
    int*   tok_e    = (int*)(ws + 768);
    float* tok_w    = (float*)(ws + 17152);
    int*   rows_tok = (int*)(ws + 33536);
    float* rows_w   = (float*)(ws + 49920);
    unsigned short* xb = (unsigned short*)(ws + 66560);
    unsigned short* h  = (unsigned short*)(ws + 66560 + (size_t)N_TOKENS * D_MODEL * 2);

    hipMemsetAsync(counts, 0, 32, stream);
    hipMemsetAsync(d_out, 0, (size_t)out_size * sizeof(float), stream);

    cvt_x_kernel<<<dim3((N_TOKENS * D_MODEL / 4 + 255) / 256), dim3(256), 0, stream>>>(x, xb);
    gate_kernel<<<dim3(N_TOKENS), dim3(64), 0, stream>>>(x, gw, counts, tok_e, tok_w);
    scan_kernel<<<dim3(1), dim3(64), 0, stream>>>(counts, offsets, fill);
    route_kernel<<<dim3((TOTAL_SLOTS + 255) / 256), dim3(256), 0, stream>>>(tok_e, tok_w, fill, rows_tok, rows_w);
    gemm1_kernel<<<dim3(D_FF / 128, 16, N_EXPERTS), dim3(256), 0, stream>>>(xb, w1, counts, offsets, rows_tok, h);
    gemm2_kernel<<<dim3(D_MODEL / 128, 16, N_EXPERTS * SPLITK2), dim3(256), 0, stream>>>(h, w2, counts, offsets, rows_tok, rows_w, out);
}

// Round 4
// 325.044 us; speedup vs baseline: 1.2667x; 1.0301x over previous
//
#include <hip/hip_runtime.h>
#include <hip/hip_bf16.h>

// ---------- types ----------
typedef short short8 __attribute__((ext_vector_type(8)));
typedef float f32x4 __attribute__((ext_vector_type(4)));

#define N_TOKENS 2048
#define D_MODEL 1024
#define D_FF 4096
#define N_EXPERTS 8
#define TOTAL_SLOTS (N_TOKENS * 2)
#define BK 32
#define SPLITK2 4
#define KC2 (D_FF / SPLITK2)   // 1024 K per gemm2 block

static __device__ __forceinline__ unsigned int f2u(float f) {
    union { float f; unsigned int u; } v; v.f = f; return v.u;
}

// fp32 -> bf16 bits, round-to-nearest-even (scalar path)
static __device__ __forceinline__ unsigned short f2bf(float f) {
    unsigned int u = f2u(f);
    unsigned int r = (u + 0x7fffu + ((u >> 16) & 1u)) >> 16;
    return (unsigned short)r;
}

// two fp32 -> packed bf16x2 (v_cvt_pk_bf16_f32)
static __device__ __forceinline__ unsigned int pk2bf(float a, float b) {
    __hip_bfloat162 t = __float22bfloat162_rn(float2{a, b});
    unsigned int u;
    __builtin_memcpy(&u, &t, 4);
    return u;
}

// async global->LDS, 16B per lane (lane l -> base + l*16)
typedef __attribute__((address_space(1))) const unsigned int GU;
typedef __attribute__((address_space(3))) unsigned int LU;
static __device__ __forceinline__ void gload_lds16(const void* g, void* l) {
    __builtin_amdgcn_global_load_lds((GU*)g, (LU*)l, 16, 0, 0);
}

// ---------- kernel 1: x fp32 -> bf16 ----------
__global__ __launch_bounds__(256) void cvt_x_kernel(const float* __restrict__ x,
                                                    unsigned short* __restrict__ xb) {
    int i = (blockIdx.x * 256 + threadIdx.x) * 4;
    if (i >= N_TOKENS * D_MODEL) return;
    float4 f = *(const float4*)(x + i);
    uint2 o;
    o.x = pk2bf(f.x, f.y);
    o.y = pk2bf(f.z, f.w);
    *(uint2*)(xb + i) = o;
}

// ---------- kernel 2: gating (exact fp32) ----------
__global__ __launch_bounds__(64) void gate_kernel(const float* __restrict__ x,
                                                  const float* __restrict__ gw,
                                                  int* __restrict__ counts,
                                                  int* __restrict__ tok_e,
                                                  float* __restrict__ tok_w) {
    const int n = blockIdx.x;
    const int lane = threadIdx.x;
    float p[N_EXPERTS];
#pragma unroll
    for (int e = 0; e < N_EXPERTS; ++e) p[e] = 0.f;
    const float* xr = x + n * D_MODEL;
    for (int d = lane; d < D_MODEL; d += 64) {
        float xv = xr[d];
#pragma unroll
        for (int e = 0; e < N_EXPERTS; ++e) p[e] += xv * gw[e * D_MODEL + d];
    }
#pragma unroll
    for (int e = 0; e < N_EXPERTS; ++e) {
        float v = p[e];
        for (int o = 32; o > 0; o >>= 1) v += __shfl_down(v, o);
        p[e] = v;
    }
    if (lane == 0) {
        int b1 = 0; float v1 = p[0];
        for (int e = 1; e < N_EXPERTS; ++e) if (p[e] > v1) { v1 = p[e]; b1 = e; }
        int b2 = -1; float v2 = -1e30f;
        for (int e = 0; e < N_EXPERTS; ++e) if (e != b1 && p[e] > v2) { v2 = p[e]; b2 = e; }
        float e2 = __expf(v2 - v1);
        float s = 1.f + e2;
        tok_e[n * 2 + 0] = b1; tok_w[n * 2 + 0] = 1.f / s;
        tok_e[n * 2 + 1] = b2; tok_w[n * 2 + 1] = e2 / s;
        atomicAdd(&counts[b1], 1);
        atomicAdd(&counts[b2], 1);
    }
}

// ---------- kernel 3: exclusive scan of 8 counts ----------
__global__ void scan_kernel(const int* __restrict__ counts,
                            int* __restrict__ offsets, int* __restrict__ fill) {
    if (threadIdx.x == 0 && blockIdx.x == 0) {
        int s = 0;
        for (int e = 0; e < N_EXPERTS; ++e) { offsets[e] = s; fill[e] = s; s += counts[e]; }
    }
}

// ---------- kernel 4: route tokens into contiguous per-expert slots ----------
__global__ __launch_bounds__(256) void route_kernel(const int* __restrict__ tok_e,
                                                    const float* __restrict__ tok_w,
                                                    int* __restrict__ fill,
                                                    int* __restrict__ rows_tok,
                                                    float* __restrict__ rows_w) {
    int i = blockIdx.x * 256 + threadIdx.x;
    if (i >= TOTAL_SLOTS) return;
    int e = tok_e[i];
    float w = tok_w[i];
    int pos = atomicAdd(&fill[e], 1);
    rows_tok[pos] = i >> 1;
    rows_w[pos] = w;
}

// ============ shared GEMM pipeline body ============
// Per step t (cur = t&1, compile-time via unroll-by-2):
//   issue A glds (2 ops, t+1) -> As[cur^1]; fence; issue B loads (4 ops, t+2)
//   ds_read frags As[cur]/Bs[cur]; 16x MFMA
//   convert B regs for t+1 (loaded at step t-1, ~2 iters in flight) -> Bs[cur^1]
//   lgkmcnt(0); vmcnt(4) (A done, B t+2 stays in flight); raw s_barrier
#define GEMM_BODY(T, CUR, BU, BF, ALn0, ALn1)                                       \
  {                                                                                 \
    const int t_ = (T);                                                             \
    const bool hasA_ = (t_ + 1 < KSTEPS);                                           \
    const bool hasB_ = (t_ + 2 < KSTEPS);                                           \
    if (hasA_) {                                                                    \
      const int k1_ = (t_ + 1) * BK;                                                \
      gload_lds16(ag0 + k1_, ALn0);                                                 \
      gload_lds16(ag1 + k1_, ALn1);                                                 \
    }                                                                               \
    asm volatile("" ::: "memory");                                                  \
    if (hasB_) {                                                                    \
      const int k2_ = (t_ + 2) * BK;                                                \
      BU##_0 = *(const float4*)(bg + k2_ + 0);                                      \
      BU##_1 = *(const float4*)(bg + k2_ + 4);                                      \
      BU##_2 = *(const float4*)(bg + k2_ + 8);                                      \
      BU##_3 = *(const float4*)(bg + k2_ + 12);                                     \
    }                                                                               \
    __builtin_amdgcn_sched_barrier(0);                                              \
    short8 af_[4], bf_[4];                                                          \
    _Pragma("unroll") for (int mi = 0; mi < 4; ++mi)                                \
      af_[mi] = *(const short8*)&As[CUR][(wm * 64 + mi * 16 + (lane & 15)) * 32 + (lane >> 4) * 8]; \
    _Pragma("unroll") for (int nj = 0; nj < 4; ++nj)                                \
      bf_[nj] = *(const short8*)&Bs[CUR][(wn * 64 + nj * 16 + (lane & 15)) * 32 + (lane >> 4) * 8]; \
    _Pragma("unroll") for (int mi = 0; mi < 4; ++mi)                                \
      _Pragma("unroll") for (int nj = 0; nj < 4; ++nj)                              \
        acc[mi][nj] = __builtin_amdgcn_mfma_f32_16x16x32_bf16(af_[mi], bf_[nj], acc[mi][nj], 0, 0, 0); \
    if (hasA_) {                                                                    \
      unsigned int bp_[8];                                                          \
      bp_[0] = pk2bf(BF##_0.x, BF##_0.y); bp_[1] = pk2bf(BF##_0.z, BF##_0.w);       \
      bp_[2] = pk2bf(BF##_1.x, BF##_1.y); bp_[3] = pk2bf(BF##_1.z, BF##_1.w);       \
      bp_[4] = pk2bf(BF##_2.x, BF##_2.y); bp_[5] = pk2bf(BF##_2.z, BF##_2.w);       \
      bp_[6] = pk2bf(BF##_3.x, BF##_3.y); bp_[7] = pk2bf(BF##_3.z, BF##_3.w);       \
      *(uint4*)&Bs[(CUR) ^ 1][brow * 32 + bcol]     = *(uint4*)&bp_[0];             \
      *(uint4*)&Bs[(CUR) ^ 1][brow * 32 + bcol + 8] = *(uint4*)&bp_[4];             \
      asm volatile("s_waitcnt lgkmcnt(0)" ::: "memory");                            \
      if (hasB_) asm volatile("s_waitcnt vmcnt(4)" ::: "memory");                   \
      else       asm volatile("s_waitcnt vmcnt(0)" ::: "memory");                   \
      __builtin_amdgcn_s_barrier();                                                 \
      asm volatile("" ::: "memory");                                                \
    }                                                                               \
  }

// Prologue: stage tile 0 (A via glds, B direct convert), preload B(1) regs.
#define GEMM_PROLOGUE(BE)                                                           \
  {                                                                                 \
    gload_lds16(ag0, al0_0);                                                        \
    gload_lds16(ag1, al1_0);                                                        \
    asm volatile("" ::: "memory");                                                  \
    float4 p0 = *(const float4*)(bg + 0);                                           \
    float4 p1 = *(const float4*)(bg + 4);                                           \
    float4 p2 = *(const float4*)(bg + 8);                                           \
    float4 p3 = *(const float4*)(bg + 12);                                          \
    BE##_0 = *(const float4*)(bg + BK + 0);                                         \
    BE##_1 = *(const float4*)(bg + BK + 4);                                         \
    BE##_2 = *(const float4*)(bg + BK + 8);                                         \
    BE##_3 = *(const float4*)(bg + BK + 12);                                        \
    __builtin_amdgcn_sched_barrier(0);                                              \
    unsigned int bp_[8];                                                            \
    bp_[0] = pk2bf(p0.x, p0.y); bp_[1] = pk2bf(p0.z, p0.w);                         \
    bp_[2] = pk2bf(p1.x, p1.y); bp_[3] = pk2bf(p1.z, p1.w);                         \
    bp_[4] = pk2bf(p2.x, p2.y); bp_[5] = pk2bf(p2.z, p2.w);                         \
    bp_[6] = pk2bf(p3.x, p3.y); bp_[7] = pk2bf(p3.z, p3.w);                         \
    *(uint4*)&Bs[0][brow * 32 + bcol]     = *(uint4*)&bp_[0];                       \
    *(uint4*)&Bs[0][brow * 32 + bcol + 8] = *(uint4*)&bp_[4];                       \
    asm volatile("s_waitcnt lgkmcnt(0)" ::: "memory");                              \
    asm volatile("s_waitcnt vmcnt(4)" ::: "memory");                                \
    __builtin_amdgcn_s_barrier();                                                   \
    asm volatile("" ::: "memory");                                                  \
  }

// ---------- kernel 5: GEMM1  h = gelu(x_gathered @ w1[e]^T), bf16 out ----------
// grid: (D_FF/128, 16, 8), block 256
__global__ __launch_bounds__(256, 3) void gemm1_kernel(const unsigned short* __restrict__ xb,
                                                       const float* __restrict__ w1,
                                                       const int* __restrict__ counts,
                                                       const int* __restrict__ offsets,
                                                       const int* __restrict__ rows_tok,
                                                       unsigned short* __restrict__ h) {
    const int e = blockIdx.z;
    const int cnt = counts[e];
    const int mt = blockIdx.y;
    if (mt * 128 >= cnt) return;
    const int off = offsets[e];
    const int nt = blockIdx.x;

    __shared__ unsigned short As[2][128 * 32];
    __shared__ unsigned short Bs[2][128 * 32];

    const int tid = threadIdx.x;
    const int lane = tid & 63;
    const int wave = tid >> 6;
    const int wm = wave >> 1, wn = wave & 1;

    const int arow = wave * 32 + (lane >> 2);
    const int ac8 = lane & 3;
    int r0 = off + mt * 128 + arow;
    int r1 = r0 + 16;
    r0 = min(r0, TOTAL_SLOTS - 1);
    r1 = min(r1, TOTAL_SLOTS - 1);
    const unsigned short* ag0 = xb + (size_t)rows_tok[r0] * D_MODEL + ac8 * 8;
    const unsigned short* ag1 = xb + (size_t)rows_tok[r1] * D_MODEL + ac8 * 8;
    unsigned short* al0_0 = &As[0][(wave * 32) * 32];
    unsigned short* al1_0 = &As[0][(wave * 32 + 16) * 32];
    unsigned short* al0_1 = &As[1][(wave * 32) * 32];
    unsigned short* al1_1 = &As[1][(wave * 32 + 16) * 32];

    const int brow = tid >> 1, bcol = (tid & 1) * 16;
    const float* bg = w1 + (size_t)e * (D_FF * D_MODEL) + (size_t)(nt * 128 + brow) * D_MODEL + bcol;

    f32x4 acc[4][4];
#pragma unroll
    for (int i = 0; i < 4; ++i)
#pragma unroll
        for (int j = 0; j < 4; ++j) acc[i][j] = (f32x4){0.f, 0.f, 0.f, 0.f};

    float4 bEn_0{0,0,0,0}, bEn_1{0,0,0,0}, bEn_2{0,0,0,0}, bEn_3{0,0,0,0};
    float4 bOn_0{0,0,0,0}, bOn_1{0,0,0,0}, bOn_2{0,0,0,0}, bOn_3{0,0,0,0};

    const int KSTEPS = D_MODEL / BK;  // 32 (even)
    GEMM_PROLOGUE(bEn)
    for (int tt = 0; tt < KSTEPS; tt += 2) {
        GEMM_BODY(tt,     0, bOn, bEn, al0_1, al1_1)
        GEMM_BODY(tt + 1, 1, bEn, bOn, al0_0, al1_0)
    }

    // epilogue: exact-erf GELU, store bf16
    const int lr = (lane >> 4) * 4, lc = lane & 15;
#pragma unroll
    for (int mi = 0; mi < 4; ++mi) {
        const int mbase = mt * 128 + wm * 64 + mi * 16 + lr;
#pragma unroll
        for (int j = 0; j < 4; ++j) {
            const int m = mbase + j;
            if (m < cnt) {
#pragma unroll
                for (int nj = 0; nj < 4; ++nj) {
                    const int n = nt * 128 + wn * 64 + nj * 16 + lc;
                    float v = acc[mi][nj][j];
                    v = 0.5f * v * (1.0f + erff(v * 0.70710678118654752f));
                    h[(size_t)(off + m) * D_FF + n] = f2bf(v);
                }
            }
        }
    }
}

// ---------- kernel 6: GEMM2  out[tok] += w_slot * (h @ w2[e]^T), split-K x4 ----------
// grid: (D_MODEL/128, 16, 8*SPLITK2), block 256
__global__ __launch_bounds__(256, 3) void gemm2_kernel(const unsigned short* __restrict__ h,
                                                       const float* __restrict__ w2,
                                                       const int* __restrict__ counts,
                                                       const int* __restrict__ offsets,
                                                       const int* __restrict__ rows_tok,
                                                       const float* __restrict__ rows_w,
                                                       float* __restrict__ out) {
    const int e = blockIdx.z >> 2;
    const int kc = blockIdx.z & 3;
    const int cnt = counts[e];
    const int mt = blockIdx.y;
    if (mt * 128 >= cnt) return;
    const int off = offsets[e];
    const int nt = blockIdx.x;

    __shared__ unsigned short As[2][128 * 32];
    __shared__ unsigned short Bs[2][128 * 32];

    const int tid = threadIdx.x;
    const int lane = tid & 63;
    const int wave = tid >> 6;
    const int wm = wave >> 1, wn = wave & 1;

    const int arow = wave * 32 + (lane >> 2);
    const int ac8 = lane & 3;
    int r0 = off + mt * 128 + arow;
    int r1 = r0 + 16;
    r0 = min(r0, TOTAL_SLOTS - 1);
    r1 = min(r1, TOTAL_SLOTS - 1);
    const unsigned short* ag0 = h + (size_t)r0 * D_FF + kc * KC2 + ac8 * 8;
    const unsigned short* ag1 = h + (size_t)r1 * D_FF + kc * KC2 + ac8 * 8;
    unsigned short* al0_0 = &As[0][(wave * 32) * 32];
    unsigned short* al1_0 = &As[0][(wave * 32 + 16) * 32];
    unsigned short* al0_1 = &As[1][(wave * 32) * 32];
    unsigned short* al1_1 = &As[1][(wave * 32 + 16) * 32];

    const int brow = tid >> 1, bcol = (tid & 1) * 16;
    const float* bg = w2 + (size_t)e * (D_MODEL * D_FF) + (size_t)(nt * 128 + brow) * D_FF
                      + kc * KC2 + bcol;

    f32x4 acc[4][4];
#pragma unroll
    for (int i = 0; i < 4; ++i)
#pragma unroll
        for (int j = 0; j < 4; ++j) acc[i][j] = (f32x4){0.f, 0.f, 0.f, 0.f};

    float4 bEn_0{0,0,0,0}, bEn_1{0,0,0,0}, bEn_2{0,0,0,0}, bEn_3{0,0,0,0};
    float4 bOn_0{0,0,0,0}, bOn_1{0,0,0,0}, bOn_2{0,0,0,0}, bOn_3{0,0,0,0};

    const int KSTEPS = KC2 / BK;  // 32 (even)
    GEMM_PROLOGUE(bEn)
    for (int tt = 0; tt < KSTEPS; tt += 2) {
        GEMM_BODY(tt,     0, bOn, bEn, al0_1, al1_1)
        GEMM_BODY(tt + 1, 1, bEn, bOn, al0_0, al1_0)
    }

    const int lr = (lane >> 4) * 4, lc = lane & 15;
#pragma unroll
    for (int mi = 0; mi < 4; ++mi) {
        const int mbase = mt * 128 + wm * 64 + mi * 16 + lr;
#pragma unroll
        for (int j = 0; j < 4; ++j) {
            const int m = mbase + j;
            if (m < cnt) {
                const int tok = rows_tok[off + m];
                const float w = rows_w[off + m];
#pragma unroll
                for (int nj = 0; nj < 4; ++nj) {
                    const int n = nt * 128 + wn * 64 + nj * 16 + lc;
                    atomicAdd(&out[(size_t)tok * D_MODEL + n], w * acc[mi][nj][j]);
                }
            }
        }
    }
}

// ---------- workspace layout ----------
//   0        counts[8]
//   256      fill[8]
//   512      offsets[8]
//   768      tok_e   [4096] int
//   17152    tok_w   [4096] float
//   33536    rows_tok[4096] int
//   49920    rows_w  [4096] float
//   66560    xb  bf16 [2048][1024]   (4 MB)
//   +4MB     h   bf16 [4096][4096]   (32 MB)

extern "C" void kernel_launch(void* const* d_in, const int* in_sizes, int n_in,
                              void* d_out, int out_size, void* d_ws, size_t ws_size,
                              hipStream_t stream) {
    const float* x  = (const float*)d_in[0];
    const float* gw = (const float*)d_in[1];
    const float* w1 = (const float*)d_in[2];
    const float* w2 = (const float*)d_in[3];
    float* out = (float*)d_out;

    char* ws = (char*)d_ws;
    int*   counts   = (int*)(ws + 0);
    int*   fill     = (int*)(ws + 256);
    int*   offsets  = (int*)(ws + 512);
    int*   tok_e    = (int*)(ws + 768);
    float* tok_w    = (float*)(ws + 17152);
    int*   rows_tok = (int*)(ws + 33536);
    float* rows_w   = (float*)(ws + 49920);
    unsigned short* xb = (unsigned short*)(ws + 66560);
    unsigned short* h  = (unsigned short*)(ws + 66560 + (size_t)N_TOKENS * D_MODEL * 2);

    hipMemsetAsync(counts, 0, 32, stream);
    hipMemsetAsync(d_out, 0, (size_t)out_size * sizeof(float), stream);

    cvt_x_kernel<<<dim3((N_TOKENS * D_MODEL / 4 + 255) / 256), dim3(256), 0, stream>>>(x, xb);
    gate_kernel<<<dim3(N_TOKENS), dim3(64), 0, stream>>>(x, gw, counts, tok_e, tok_w);
    scan_kernel<<<dim3(1), dim3(64), 0, stream>>>(counts, offsets, fill);
    route_kernel<<<dim3((TOTAL_SLOTS + 255) / 256), dim3(256), 0, stream>>>(tok_e, tok_w, fill, rows_tok, rows_w);
    gemm1_kernel<<<dim3(D_FF / 128, 16, N_EXPERTS), dim3(256), 0, stream>>>(xb, w1, counts, offsets, rows_tok, h);
    gemm2_kernel<<<dim3(D_MODEL / 128, 16, N_EXPERTS * SPLITK2), dim3(256), 0, stream>>>(h, w2, counts, offsets, rows_tok, rows_w, out);
}